// Round 7
// baseline (362.829 us; speedup 1.0000x reference)
//
#include <hip/hip_runtime.h>

#define N_NODES 8192
#define N_EDGES 131072

using short8 = __attribute__((ext_vector_type(8))) short;
using f32x4  = __attribute__((ext_vector_type(4))) float;

__device__ __forceinline__ float rcpf(float x){ return __builtin_amdgcn_rcpf(x); }
__device__ __forceinline__ float sigm(float x){ return rcpf(1.0f+__expf(-x)); }
__device__ __forceinline__ float ftanh(float x){ float e=__expf(2.0f*x); return (e-1.0f)*rcpf(e+1.0f); }
__device__ __forceinline__ float swishf(float x){ return x*sigm(x); }
__device__ __forceinline__ float leaky(float x){ return x>=0.0f? x : 0.2f*x; }
__device__ __forceinline__ float dot4(float4 a, float4 b){ return a.x*b.x+a.y*b.y+a.z*b.z+a.w*b.w; }
__device__ __forceinline__ short f2bf(float x){
  unsigned u=__float_as_uint(x);
  unsigned r=(u + 0x7fffu + ((u>>16)&1u))>>16;
  return (short)r;
}
// packed bf16 convert: low16 = bf16(a), high16 = bf16(b), RNE
__device__ __forceinline__ int cvtpk(float a, float b){
  int r; asm("v_cvt_pk_bf16_f32 %0, %1, %2" : "=v"(r) : "v"(a), "v"(b)); return r;
}

__device__ __forceinline__ float wave_rsum(float v){
  #pragma unroll
  for(int m=32;m;m>>=1) v+=__shfl_xor(v,m);
  return v;
}

// ---------------- CSR build ----------------
__global__ __launch_bounds__(256) void hist_kernel(const int* __restrict__ dst, int* __restrict__ cnt){
  int e=blockIdx.x*256+threadIdx.x;
  if(e<N_EDGES) atomicAdd(&cnt[dst[e]],1);
}

__global__ __launch_bounds__(1024) void scan_kernel(const int* __restrict__ cnt, int* __restrict__ rowptr, int* __restrict__ cursor){
  __shared__ int sums[1024];
  int t=threadIdx.x; int base=t*8;
  int local[8]; int s=0;
  #pragma unroll
  for(int i=0;i<8;++i){ local[i]=s; s+=cnt[base+i]; }
  sums[t]=s; __syncthreads();
  for(int off=1;off<1024;off<<=1){
    int v=(t>=off)?sums[t-off]:0;
    __syncthreads();
    sums[t]+=v;
    __syncthreads();
  }
  int offset=(t>0)?sums[t-1]:0;
  #pragma unroll
  for(int i=0;i<8;++i){ int v=offset+local[i]; rowptr[base+i]=v; cursor[base+i]=v; }
  if(t==1023) rowptr[N_NODES]=sums[1023];
}

__global__ __launch_bounds__(256) void scatter_kernel(const int* __restrict__ src, const int* __restrict__ dst,
                                                      int* __restrict__ cursor, int* __restrict__ csr_src){
  int e=blockIdx.x*256+threadIdx.x;
  if(e<N_EDGES){
    int slot=atomicAdd(&cursor[dst[e]],1);
    csr_src[slot]=src[e];
  }
}

// ---------------- fused fp32 -> bf16 weight prep + edge-weight collapse ----------------
__global__ __launch_bounds__(256) void prep_bf16_kernel(
    const float* __restrict__ lem_hid_w, const float* __restrict__ lem_z_w,
    const float* __restrict__ mlp1_w, const float* __restrict__ mlp2_w,
    const float* __restrict__ gate_lin_w, const float* __restrict__ gnn_lin_w,
    const float* __restrict__ gate_ew, const float* __restrict__ gnn_ew,
    const float* __restrict__ gate_ae, const float* __restrict__ gnn_ae,
    short* __restrict__ whb, short* __restrict__ wzb, short* __restrict__ w1b,
    short* __restrict__ w2b, short* __restrict__ wlin16, float* __restrict__ we)
{
  int i=blockIdx.x*256+threadIdx.x;
  if(i<49152){ whb[i]=f2bf(lem_hid_w[i]); return; }
  if(i<65536){ int k=i-49152; wzb[k]=f2bf(lem_z_w[k]); return; }
  if(i<81920){ int k=i-65536; w1b[k]=f2bf(mlp1_w[k]); return; }
  if(i<98304){ int k=i-81920; w2b[k]=f2bf(mlp2_w[k]); return; }
  if(i<294912){
    int k=i-98304;                 // [6][2][16384]
    int l=k>>15, which=(k>>14)&1, r=k&16383;
    const float* s = which? gnn_lin_w + l*16384 + r : gate_lin_w + l*16384 + r;
    wlin16[k]=f2bf(*s);
    return;
  }
  int idx=i-294912;
  if(idx>=12*51) return;
  int g=idx/51, k=idx%51, l=g>>1;
  const float* ew = (g&1)? gnn_ew + l*128*51 : gate_ew + l*128*51;
  const float* ae = (g&1)? gnn_ae + l*128    : gate_ae + l*128;
  float s=0.f;
  for(int f=0;f<128;++f) s+=ew[f*51+k]*ae[f];
  we[idx]=s;
}

__global__ __launch_bounds__(128) void gsc_kernel(const float* __restrict__ u, const float* __restrict__ pos,
                                                  const float* __restrict__ we, float* __restrict__ gsc){
  int n=blockIdx.x*128+threadIdx.x;
  float uv[50];
  #pragma unroll
  for(int k=0;k<50;++k) uv[k]=u[n*50+k];
  float px=pos[n*2+1]*(1.0f/16.0f);
  for(int g=0;g<12;++g){
    const float* w=we+g*51;
    float s=w[50]*px;
    #pragma unroll
    for(int k=0;k<50;++k) s+=w[k]*uv[k];
    gsc[g*N_NODES+n]=s;
  }
}

// ---------------- shared device pieces ----------------
// GAT transform for 16 nodes (h16 = bf16 swizzled [16][128]); 8 waves.
__device__ __forceinline__ void transform_phase(
    int tid, int n0,
    const short* __restrict__ h16, short* __restrict__ xts,
    float* __restrict__ ssred, float* __restrict__ sdred,
    const short* __restrict__ wl,
    const float* __restrict__ a_sg, const float* __restrict__ a_dg,
    const float* __restrict__ a_sm, const float* __restrict__ a_dm,
    const float* __restrict__ gsc_g, const float* __restrict__ gsc_m,
    short* __restrict__ xt_out, float* __restrict__ ss_out, float* __restrict__ sd_out)
{
  const int lane=tid&63, w=tid>>6;
  const int cg=w&1, ch=w>>1;
  const int r16=lane&15, kq=lane>>4;
  __syncthreads();
  short8 afr[4];
  #pragma unroll
  for(int kk=0;kk<4;++kk)
    afr[kk]=*(const short8*)&h16[r16*128 + ((kk*32+kq*8) ^ ((r16&7)<<3))];
  const short* wb = wl + cg*16384;
  const float* as_ = cg? a_sm : a_sg;
  const float* ad_ = cg? a_dm : a_dg;
  float ssp[4]={0,0,0,0}, sdp[4]={0,0,0,0};
  #pragma unroll
  for(int ci=0;ci<2;++ci){
    int c0=(ch*2+ci)*16;
    f32x4 acc={0.f,0.f,0.f,0.f};
    #pragma unroll
    for(int kk=0;kk<4;++kk){
      short8 b=*(const short8*)(wb + (c0+r16)*128 + kk*32 + kq*8);
      acc=__builtin_amdgcn_mfma_f32_16x16x32_bf16(afr[kk],b,acc,0,0,0);
    }
    float av=as_[c0+r16], dv=ad_[c0+r16];
    #pragma unroll
    for(int r=0;r<4;++r){
      ssp[r]+=acc[r]*av; sdp[r]+=acc[r]*dv;
      xts[(kq*4+r)*256 + cg*128 + c0 + r16]=f2bf(acc[r]);
    }
  }
  #pragma unroll
  for(int m=1;m<16;m<<=1){
    #pragma unroll
    for(int r=0;r<4;++r){ ssp[r]+=__shfl_xor(ssp[r],m); sdp[r]+=__shfl_xor(sdp[r],m); }
  }
  if(r16==0){
    #pragma unroll
    for(int r=0;r<4;++r){ ssred[w*16+kq*4+r]=ssp[r]; sdred[w*16+kq*4+r]=sdp[r]; }
  }
  __syncthreads();
  if(tid<32){
    int node=tid&15, cg2=tid>>4;
    float sv=0.f, dv=0.f;
    #pragma unroll
    for(int c2=0;c2<4;++c2){ sv+=ssred[(c2*2+cg2)*16+node]; dv+=sdred[(c2*2+cg2)*16+node]; }
    float gv=(cg2? gsc_m:gsc_g)[n0+node];
    ss_out[2*(n0+node)+cg2]=sv+gv;
    sd_out[2*(n0+node)+cg2]=dv-gv;
  }
  {
    const short8* sp=(const short8*)xts;
    short8* dp=(short8*)(xt_out + (size_t)n0*256);
    dp[tid]=sp[tid];
  }
}

// Dual-GAT softmax aggregate for one node by one wave.
// Single pass (softmax shift-invariance; clamp 60 guards overflow).
// LDS chunk staging (1 ds_write + broadcast b128 reads, replaces 3 shfl/edge)
// + 16-deep row-load batches for memory-level parallelism.
__device__ __forceinline__ float4 aggregate_node(
    int n, int lane, float4* __restrict__ stgw,
    const int* __restrict__ rowptr, const int* __restrict__ csr_src,
    const short* __restrict__ xt_in, const float* __restrict__ ss_in, const float* __restrict__ sd_in,
    const float* __restrict__ bias_g, const float* __restrict__ bias_m,
    const float* __restrict__ h)
{
  const int s0=rowptr[n], deg=rowptr[n+1]-s0;
  const float2 sdv=*(const float2*)(sd_in+2*n);
  const float bg=sdv.x, bm=sdv.y;
  // prefetch the h row for the final blend (latency hides under the gather)
  float4 hv={0.f,0.f,0.f,0.f};
  if(lane<32) hv=*(const float4*)(h + (size_t)n*128 + 4*lane);
  float dg=0.f,dm=0.f, acc0=0.f,acc1=0.f,acc2=0.f,acc3=0.f;
  for(int c=0;c<deg;c+=64){
    int i=c+lane, s=0; float eg=0.f, em=0.f;
    if(i<deg){
      s=csr_src[s0+i];
      float2 ssv=*(const float2*)(ss_in+2*s);
      eg=__expf(fminf(leaky(ssv.x+bg),60.f));
      em=__expf(fminf(leaky(ssv.y+bm),60.f));
      dg+=eg; dm+=em;
    }
    float4 st; st.x=__int_as_float(s); st.y=eg; st.z=em; st.w=0.f;
    stgw[lane]=st;
    __threadfence_block();
    int cnt=min(64,deg-c);
    for(int cb=0;cb<cnt;cb+=16){
      int sj[16]; float wj[16];
      #pragma unroll
      for(int j=0;j<16;++j){
        int idx=cb+j;
        float4 ev=stgw[idx<cnt? idx : cb];   // dup slot for tail (weight forced 0 below)
        sj[j]=__float_as_int(ev.x);
        wj[j]=(idx<cnt)? (lane<32? ev.y : ev.z) : 0.f;
      }
      uint2 rows[16];
      #pragma unroll
      for(int j=0;j<16;++j)
        rows[j]=*(const uint2*)(xt_in + (size_t)sj[j]*256 + 4*lane);
      #pragma unroll
      for(int j=0;j<16;++j){
        float wv=wj[j];
        unsigned p0=rows[j].x, p1=rows[j].y;
        acc0+=wv*__uint_as_float(p0<<16);
        acc1+=wv*__uint_as_float(p0&0xffff0000u);
        acc2+=wv*__uint_as_float(p1<<16);
        acc3+=wv*__uint_as_float(p1&0xffff0000u);
      }
    }
  }
  dg=wave_rsum(dg); dm=wave_rsum(dm);
  float rr = lane<32? rcpf(dg+1e-16f) : rcpf(dm+1e-16f);
  const float* bp = lane<32? bias_g+4*lane : bias_m+4*(lane-32);
  float4 bv=*(const float4*)bp;
  float o0=acc0*rr+bv.x, o1=acc1*rr+bv.y, o2=acc2*rr+bv.z, o3=acc3*rr+bv.w;
  float s0_=sigm(o0), s1_=sigm(o1), s2_=sigm(o2), s3_=sigm(o3);
  float v0=lane<32? s0_:o0*s0_;
  float v1=lane<32? s1_:o1*s1_;
  float v2=lane<32? s2_:o2*s2_;
  float v3=lane<32? s3_:o3*s3_;
  float m0=__shfl_xor(v0,32), m1=__shfl_xor(v1,32), m2=__shfl_xor(v2,32), m3=__shfl_xor(v3,32);
  float4 r;
  if(lane<32){
    r.x=(1.0f-v0)*hv.x+v0*m0;
    r.y=(1.0f-v1)*hv.y+v1*m1;
    r.z=(1.0f-v2)*hv.z+v2*m2;
    r.w=(1.0f-v3)*hv.w+v3*m3;
  } else { r.x=r.y=r.z=r.w=0.f; }
  return r;
}

// ---------------- LEM scan (MFMA, 32 nodes/block) + MLP + GAT transform layer 0 ----------------
__global__ __launch_bounds__(512,2) void lem_t0_kernel(
    const float* __restrict__ u, const float* __restrict__ pos,
    const float* __restrict__ Wi, const float* __restrict__ bi,
    const short* __restrict__ whb, const float* __restrict__ bh,
    const short* __restrict__ wzb, const float* __restrict__ bz,
    const short* __restrict__ w1b, const float* __restrict__ b1,
    const short* __restrict__ w2b, const float* __restrict__ b2,
    float* __restrict__ hout,
    const short* __restrict__ wl,
    const float* __restrict__ a_sg, const float* __restrict__ a_dg,
    const float* __restrict__ a_sm, const float* __restrict__ a_dm,
    const float* __restrict__ gsc_g, const float* __restrict__ gsc_m,
    short* __restrict__ xt_out, float* __restrict__ ss_out, float* __restrict__ sd_out)
{
  __shared__ short y16[2][16*128];
  __shared__ short z16[2][16*128];
  __shared__ float u_s[32*50];
  __shared__ short h16[16*128];
  __shared__ short xts[16*256];
  __shared__ float ssred[128], sdred[128];

  const int tid=threadIdx.x, lane=tid&63, w=tid>>6;
  const int node=lane&15, q=lane>>4;
  const int n7=node&7;
  const int n0=blockIdx.x*32;

  for(int i=tid;i<32*50;i+=512) u_s[i]=u[n0*50+i];
  for(int i=tid;i<2*16*64;i+=512) ((int*)y16)[i]=0;

  const float px0=pos[(n0+node)*2+1]*(1.0f/16.0f),    pt0=pos[(n0+node)*2+0]*0.25f;
  const float px1=pos[(n0+16+node)*2+1]*(1.0f/16.0f), pt1=pos[(n0+16+node)*2+0]*0.25f;

  float bb[4][4], wix[4][4], wiw[4][4], wiy[4][4], wiz[4][4];
  #pragma unroll
  for(int gg=0; gg<4; ++gg){
    #pragma unroll
    for(int r=0;r<4;++r){
      int fr = w*16+q*4+r;
      int row = gg*128+fr;
      float4 wi = *(const float4*)(Wi+4*row);
      bb[gg][r] = bi[row] + ((gg<3)? bh[row] : bz[fr]);
      wix[gg][r]=wi.x; wiw[gg][r]=wi.w; wiy[gg][r]=wi.y; wiz[gg][r]=wi.z;
    }
  }

  short8 whf[3][4];
  #pragma unroll
  for(int gg=0;gg<3;++gg)
    #pragma unroll
    for(int kk=0;kk<4;++kk)
      whf[gg][kk]=*(const short8*)(whb + (gg*128 + w*16 + node)*128 + kk*32 + q*8);
  short8 wzf[4];
  #pragma unroll
  for(int kk=0;kk<4;++kk)
    wzf[kk]=*(const short8*)(wzb + (w*16 + node)*128 + kk*32 + q*8);

  float yr0[4]={0.f,0.f,0.f,0.f}, zr0[4]={0.f,0.f,0.f,0.f};
  float yr1[4]={0.f,0.f,0.f,0.f}, zr1[4]={0.f,0.f,0.f,0.f};
  float msb0[4], i4s0[4], msb1[4], i4s1[4];
  const int wrslot = (w*16+q*4) ^ (n7<<3);
  const int rdbase = n7<<3;
  __syncthreads();

  for(int t=0;t<25;++t){
    const float tf=(float)(t+1);
    {
      f32x4 h1a={0.f,0.f,0.f,0.f}, h2a=h1a, h3a=h1a;
      #pragma unroll
      for(int kk=0;kk<4;++kk){
        short8 yb=*(const short8*)&y16[0][node*128 + ((kk*32 + q*8) ^ rdbase)];
        h1a=__builtin_amdgcn_mfma_f32_16x16x32_bf16(whf[0][kk],yb,h1a,0,0,0);
        h2a=__builtin_amdgcn_mfma_f32_16x16x32_bf16(whf[1][kk],yb,h2a,0,0,0);
        h3a=__builtin_amdgcn_mfma_f32_16x16x32_bf16(whf[2][kk],yb,h3a,0,0,0);
      }
      const float u0=u_s[node*50+t], u1=u_s[node*50+25+t];
      const float ts=pt0+0.04f*tf;
      #pragma unroll
      for(int r=0;r<4;++r){
        float i1=bb[0][r]+wix[0][r]*px0+wiw[0][r]*ts+wiy[0][r]*u0+wiz[0][r]*u1;
        float i2=bb[1][r]+wix[1][r]*px0+wiw[1][r]*ts+wiy[1][r]*u0+wiz[1][r]*u1;
        float i3=bb[2][r]+wix[2][r]*px0+wiw[2][r]*ts+wiy[2][r]*u0+wiz[2][r]*u1;
        i4s0[r] =bb[3][r]+wix[3][r]*px0+wiw[3][r]*ts+wiy[3][r]*u0+wiz[3][r]*u1;
        msb0[r]=sigm(i1+h1a[r]);
        float ms=sigm(i2+h2a[r]);
        zr0[r]=(1.0f-ms)*zr0[r]+ms*ftanh(i3+h3a[r]);
      }
      int2 zz; zz.x=cvtpk(zr0[0],zr0[1]); zz.y=cvtpk(zr0[2],zr0[3]);
      *(int2*)&z16[0][node*128 + wrslot]=zz;
    }
    {
      f32x4 h1a={0.f,0.f,0.f,0.f}, h2a=h1a, h3a=h1a;
      #pragma unroll
      for(int kk=0;kk<4;++kk){
        short8 yb=*(const short8*)&y16[1][node*128 + ((kk*32 + q*8) ^ rdbase)];
        h1a=__builtin_amdgcn_mfma_f32_16x16x32_bf16(whf[0][kk],yb,h1a,0,0,0);
        h2a=__builtin_amdgcn_mfma_f32_16x16x32_bf16(whf[1][kk],yb,h2a,0,0,0);
        h3a=__builtin_amdgcn_mfma_f32_16x16x32_bf16(whf[2][kk],yb,h3a,0,0,0);
      }
      const float u0=u_s[(16+node)*50+t], u1=u_s[(16+node)*50+25+t];
      const float ts=pt1+0.04f*tf;
      #pragma unroll
      for(int r=0;r<4;++r){
        float i1=bb[0][r]+wix[0][r]*px1+wiw[0][r]*ts+wiy[0][r]*u0+wiz[0][r]*u1;
        float i2=bb[1][r]+wix[1][r]*px1+wiw[1][r]*ts+wiy[1][r]*u0+wiz[1][r]*u1;
        float i3=bb[2][r]+wix[2][r]*px1+wiw[2][r]*ts+wiy[2][r]*u0+wiz[2][r]*u1;
        i4s1[r] =bb[3][r]+wix[3][r]*px1+wiw[3][r]*ts+wiy[3][r]*u0+wiz[3][r]*u1;
        msb1[r]=sigm(i1+h1a[r]);
        float ms=sigm(i2+h2a[r]);
        zr1[r]=(1.0f-ms)*zr1[r]+ms*ftanh(i3+h3a[r]);
      }
      int2 zz; zz.x=cvtpk(zr1[0],zr1[1]); zz.y=cvtpk(zr1[2],zr1[3]);
      *(int2*)&z16[1][node*128 + wrslot]=zz;
    }
    __syncthreads();
    {
      f32x4 zw={0.f,0.f,0.f,0.f};
      #pragma unroll
      for(int kk=0;kk<4;++kk){
        short8 zb=*(const short8*)&z16[0][node*128 + ((kk*32 + q*8) ^ rdbase)];
        zw=__builtin_amdgcn_mfma_f32_16x16x32_bf16(wzf[kk],zb,zw,0,0,0);
      }
      #pragma unroll
      for(int r=0;r<4;++r)
        yr0[r]=(1.0f-msb0[r])*yr0[r]+msb0[r]*ftanh(zw[r]+i4s0[r]);
      int2 yy; yy.x=cvtpk(yr0[0],yr0[1]); yy.y=cvtpk(yr0[2],yr0[3]);
      *(int2*)&y16[0][node*128 + wrslot]=yy;
    }
    {
      f32x4 zw={0.f,0.f,0.f,0.f};
      #pragma unroll
      for(int kk=0;kk<4;++kk){
        short8 zb=*(const short8*)&z16[1][node*128 + ((kk*32 + q*8) ^ rdbase)];
        zw=__builtin_amdgcn_mfma_f32_16x16x32_bf16(wzf[kk],zb,zw,0,0,0);
      }
      #pragma unroll
      for(int r=0;r<4;++r)
        yr1[r]=(1.0f-msb1[r])*yr1[r]+msb1[r]*ftanh(zw[r]+i4s1[r]);
      int2 yy; yy.x=cvtpk(yr1[0],yr1[1]); yy.y=cvtpk(yr1[2],yr1[3]);
      *(int2*)&y16[1][node*128 + wrslot]=yy;
    }
    __syncthreads();
  }

  #pragma unroll
  for(int nt=0;nt<2;++nt){
    {
      short8 w1f[4];
      #pragma unroll
      for(int kk=0;kk<4;++kk)
        w1f[kk]=*(const short8*)(w1b + (w*16 + node)*128 + kk*32 + q*8);
      float4 b1v=*(const float4*)(b1 + w*16 + q*4);
      f32x4 a={0.f,0.f,0.f,0.f};
      #pragma unroll
      for(int kk=0;kk<4;++kk){
        short8 yb=*(const short8*)&y16[nt][node*128 + ((kk*32 + q*8) ^ rdbase)];
        a=__builtin_amdgcn_mfma_f32_16x16x32_bf16(w1f[kk],yb,a,0,0,0);
      }
      float t0=swishf(a[0]+b1v.x), t1=swishf(a[1]+b1v.y);
      float t2=swishf(a[2]+b1v.z), t3=swishf(a[3]+b1v.w);
      int2 zz; zz.x=cvtpk(t0,t1); zz.y=cvtpk(t2,t3);
      *(int2*)&z16[nt][node*128 + wrslot]=zz;
    }
    __syncthreads();
    {
      short8 w2f[4];
      #pragma unroll
      for(int kk=0;kk<4;++kk)
        w2f[kk]=*(const short8*)(w2b + (w*16 + node)*128 + kk*32 + q*8);
      float4 b2v=*(const float4*)(b2 + w*16 + q*4);
      f32x4 a={0.f,0.f,0.f,0.f};
      #pragma unroll
      for(int kk=0;kk<4;++kk){
        short8 zb=*(const short8*)&z16[nt][node*128 + ((kk*32 + q*8) ^ rdbase)];
        a=__builtin_amdgcn_mfma_f32_16x16x32_bf16(w2f[kk],zb,a,0,0,0);
      }
      float h0=swishf(a[0]+b2v.x), h1=swishf(a[1]+b2v.y);
      float h2=swishf(a[2]+b2v.z), h3=swishf(a[3]+b2v.w);
      float4 hv; hv.x=h0; hv.y=h1; hv.z=h2; hv.w=h3;
      *(float4*)(hout + (size_t)(n0+nt*16+node)*128 + w*16+q*4)=hv;
      int2 hb; hb.x=cvtpk(h0,h1); hb.y=cvtpk(h2,h3);
      *(int2*)&h16[node*128 + wrslot]=hb;
    }
    transform_phase(tid,n0+nt*16,h16,xts,ssred,sdred,wl,a_sg,a_dg,a_sm,a_dm,gsc_g,gsc_m,xt_out,ss_out,sd_out);
  }
}

// ---------------- fused: aggregate(layer l) + transform(layer l+1) ----------------
__global__ __launch_bounds__(512,2) void gat_fused_kernel(
    const int* __restrict__ rowptr, const int* __restrict__ csr_src,
    const short* __restrict__ xt_in, const float* __restrict__ ss_in, const float* __restrict__ sd_in,
    const float* __restrict__ bias_g, const float* __restrict__ bias_m,
    float* __restrict__ h,
    const short* __restrict__ wl,
    const float* __restrict__ a_sg, const float* __restrict__ a_dg,
    const float* __restrict__ a_sm, const float* __restrict__ a_dm,
    const float* __restrict__ gsc_g, const float* __restrict__ gsc_m,
    short* __restrict__ xt_out, float* __restrict__ ss_out, float* __restrict__ sd_out)
{
  __shared__ short h16[16*128];
  __shared__ short xts[16*256];
  __shared__ float ssred[128], sdred[128];
  __shared__ float4 stg[8][64];
  const int tid=threadIdx.x, lane=tid&63, w=tid>>6;
  const int n0=blockIdx.x*16;
  #pragma unroll
  for(int which=0;which<2;++which){
    int row=w*2+which, n=n0+row;
    float4 hv=aggregate_node(n,lane,stg[w],rowptr,csr_src,xt_in,ss_in,sd_in,bias_g,bias_m,h);
    if(lane<32){
      *(float4*)(h+(size_t)n*128+4*lane)=hv;
      int2 hb; hb.x=cvtpk(hv.x,hv.y); hb.y=cvtpk(hv.z,hv.w);
      *(int2*)&h16[row*128 + ((4*lane) ^ ((row&7)<<3))]=hb;
    }
  }
  transform_phase(tid,n0,h16,xts,ssred,sdred,wl,a_sg,a_dg,a_sm,a_dm,gsc_g,gsc_m,xt_out,ss_out,sd_out);
}

// ---------------- fused: aggregate(layer 5) + decoder ----------------
__global__ __launch_bounds__(512,2) void gat_last_decoder_kernel(
    const int* __restrict__ rowptr, const int* __restrict__ csr_src,
    const short* __restrict__ xt_in, const float* __restrict__ ss_in, const float* __restrict__ sd_in,
    const float* __restrict__ bias_g, const float* __restrict__ bias_m,
    const float* __restrict__ h, const float* __restrict__ u,
    const float* __restrict__ Wd, const float* __restrict__ bd,
    const float* __restrict__ w1, const float* __restrict__ b1,
    const float* __restrict__ w2, const float* __restrict__ b2,
    float* __restrict__ out)
{
  __shared__ float hdec[16*128];
  __shared__ float h2[16][2][128];
  __shared__ float c1[16][8][38];
  __shared__ float w1s[256], w2s[224], b1s[8], b2s[2];
  __shared__ float4 stg[8][64];
  const int tid=threadIdx.x, lane=tid&63, w=tid>>6;
  const int n0=blockIdx.x*16;
  if(tid<256) w1s[tid]=w1[tid];
  else if(tid<480) w2s[tid-256]=w2[tid-256];
  else if(tid<488) b1s[tid-480]=b1[tid-480];
  else if(tid<490) b2s[tid-488]=b2[tid-488];
  #pragma unroll
  for(int which=0;which<2;++which){
    int row=w*2+which, n=n0+row;
    float4 hv=aggregate_node(n,lane,stg[w],rowptr,csr_src,xt_in,ss_in,sd_in,bias_g,bias_m,h);
    if(lane<32) *(float4*)&hdec[row*128+4*lane]=hv;
  }
  __syncthreads();
  {
    int o=tid&255, grp=tid>>8;
    const float4* wp=(const float4*)(Wd + o*128);
    float acc[8];
    #pragma unroll
    for(int n=0;n<8;++n) acc[n]=0.f;
    for(int k=0;k<32;++k){
      float4 wv=wp[k];
      #pragma unroll
      for(int n=0;n<8;++n){ float4 hval=*(const float4*)&hdec[(grp*8+n)*128+k*4]; acc[n]+=dot4(wv,hval); }
    }
    float bdv=bd[o];
    int chn=o>>7, p=o&127;
    #pragma unroll
    for(int n=0;n<8;++n) h2[grp*8+n][chn][p]=swishf(acc[n]+bdv);
  }
  __syncthreads();
  for(int idx=tid; idx<16*8*38; idx+=512){
    int n=idx/(8*38); int r=idx%(8*38); int oc=r/38, p=r%38;
    float acc=b1s[oc];
    const float* ww=&w1s[oc*32];
    #pragma unroll
    for(int ic=0;ic<2;++ic)
      #pragma unroll
      for(int k=0;k<16;++k) acc+=ww[ic*16+k]*h2[n][ic][3*p+k];
    c1[n][oc][p]=swishf(acc);
  }
  __syncthreads();
  for(int idx=tid; idx<16*2*25; idx+=512){
    int n=idx/50; int r=idx%50; int oc=r/25, p=r%25;
    float acc=b2s[oc];
    const float* ww=&w2s[oc*112];
    #pragma unroll
    for(int ic=0;ic<8;++ic)
      #pragma unroll
      for(int k=0;k<14;++k) acc+=ww[ic*14+k]*c1[n][ic][p+k];
    int col=oc*25+p;
    out[(n0+n)*50+col]=u[(n0+n)*50+col]+0.04f*(float)(p+1)*acc;
  }
}

extern "C" void kernel_launch(void* const* d_in, const int* in_sizes, int n_in,
                              void* d_out, int out_size, void* d_ws, size_t ws_size,
                              hipStream_t stream)
{
  const float* u          =(const float*)d_in[0];
  const float* pos        =(const float*)d_in[1];
  const int*   ei         =(const int*)d_in[2];
  const float* lem_inp_w  =(const float*)d_in[3];
  const float* lem_inp_b  =(const float*)d_in[4];
  const float* lem_hid_w  =(const float*)d_in[5];
  const float* lem_hid_b  =(const float*)d_in[6];
  const float* lem_z_w    =(const float*)d_in[7];
  const float* lem_z_b    =(const float*)d_in[8];
  const float* mlp1_w     =(const float*)d_in[9];
  const float* mlp1_b     =(const float*)d_in[10];
  const float* mlp2_w     =(const float*)d_in[11];
  const float* mlp2_b     =(const float*)d_in[12];
  const float* gnn_lin_w  =(const float*)d_in[13];
  const float* gnn_edge_w =(const float*)d_in[14];
  const float* gnn_att_src=(const float*)d_in[15];
  const float* gnn_att_dst=(const float*)d_in[16];
  const float* gnn_att_edge=(const float*)d_in[17];
  const float* gnn_bias   =(const float*)d_in[18];
  const float* gate_lin_w =(const float*)d_in[19];
  const float* gate_edge_w=(const float*)d_in[20];
  const float* gate_att_src=(const float*)d_in[21];
  const float* gate_att_dst=(const float*)d_in[22];
  const float* gate_att_edge=(const float*)d_in[23];
  const float* gate_bias  =(const float*)d_in[24];
  const float* dbl_w      =(const float*)d_in[25];
  const float* dbl_b      =(const float*)d_in[26];
  const float* conv1_w    =(const float*)d_in[27];
  const float* conv1_b    =(const float*)d_in[28];
  const float* conv2_w    =(const float*)d_in[29];
  const float* conv2_b    =(const float*)d_in[30];
  float* out=(float*)d_out;

  char* ws=(char*)d_ws;
  size_t off=0;
  auto alloc=[&](size_t bytes)->char*{ char* p=ws+off; off+=(bytes+255)&~(size_t)255; return p; };
  float* h    =(float*)alloc((size_t)N_NODES*128*4);
  short* xtA  =(short*)alloc((size_t)N_NODES*256*2);
  short* xtB  =(short*)alloc((size_t)N_NODES*256*2);
  float* ssA  =(float*)alloc((size_t)N_NODES*2*4);
  float* ssB  =(float*)alloc((size_t)N_NODES*2*4);
  float* sdA  =(float*)alloc((size_t)N_NODES*2*4);
  float* sdB  =(float*)alloc((size_t)N_NODES*2*4);
  float* gsc  =(float*)alloc((size_t)12*N_NODES*4);
  float* wearr=(float*)alloc(12*51*4);
  int* cnt    =(int*)alloc(N_NODES*4);
  int* rowptr =(int*)alloc((N_NODES+8)*4);
  int* cursor =(int*)alloc(N_NODES*4);
  int* csrsrc =(int*)alloc((size_t)N_EDGES*4);
  short* whb  =(short*)alloc(384*128*2);
  short* wzb  =(short*)alloc(128*128*2);
  short* w1b  =(short*)alloc(128*128*2);
  short* w2b  =(short*)alloc(128*128*2);
  short* wlin16=(short*)alloc((size_t)6*2*128*128*2);

  const int* src=ei;
  const int* dst=ei+N_EDGES;

  hipMemsetAsync(cnt,0,N_NODES*4,stream);
  hist_kernel<<<N_EDGES/256,256,0,stream>>>(dst,cnt);
  scan_kernel<<<1,1024,0,stream>>>(cnt,rowptr,cursor);
  scatter_kernel<<<N_EDGES/256,256,0,stream>>>(src,dst,cursor,csrsrc);
  prep_bf16_kernel<<<(294912+612+255)/256,256,0,stream>>>(lem_hid_w,lem_z_w,mlp1_w,mlp2_w,
                                                      gate_lin_w,gnn_lin_w,
                                                      gate_edge_w,gnn_edge_w,gate_att_edge,gnn_att_edge,
                                                      whb,wzb,w1b,w2b,wlin16,wearr);
  gsc_kernel<<<N_NODES/128,128,0,stream>>>(u,pos,wearr,gsc);

  short* xtbuf[2]={xtA,xtB};
  float* ssbuf[2]={ssA,ssB};
  float* sdbuf[2]={sdA,sdB};

  lem_t0_kernel<<<N_NODES/32,512,0,stream>>>(u,pos,lem_inp_w,lem_inp_b,whb,lem_hid_b,
      wzb,lem_z_b,w1b,mlp1_b,w2b,mlp2_b,h,
      wlin16,
      gate_att_src, gate_att_dst, gnn_att_src, gnn_att_dst,
      gsc, gsc+(size_t)N_NODES,
      xtbuf[0], ssbuf[0], sdbuf[0]);

  for(int l=0;l<5;++l){
    int in=l&1, o2=(l+1)&1;
    gat_fused_kernel<<<N_NODES/16,512,0,stream>>>(rowptr,csrsrc,
      xtbuf[in],ssbuf[in],sdbuf[in],
      gate_bias+l*128, gnn_bias+l*128, h,
      wlin16+(size_t)(l+1)*2*16384,
      gate_att_src+(l+1)*128, gate_att_dst+(l+1)*128,
      gnn_att_src+(l+1)*128, gnn_att_dst+(l+1)*128,
      gsc+(size_t)(2*(l+1))*N_NODES, gsc+(size_t)(2*(l+1)+1)*N_NODES,
      xtbuf[o2], ssbuf[o2], sdbuf[o2]);
  }

  gat_last_decoder_kernel<<<N_NODES/16,512,0,stream>>>(rowptr,csrsrc,
      xtbuf[1],ssbuf[1],sdbuf[1],
      gate_bias+5*128, gnn_bias+5*128, h, u,
      dbl_w, dbl_b, conv1_w, conv1_b, conv2_w, conv2_b, out);
}

// Round 9
// 356.765 us; speedup vs baseline: 1.0170x; 1.0170x over previous
//
#include <hip/hip_runtime.h>
#include <hip/hip_cooperative_groups.h>

#define N_NODES 8192
#define N_EDGES 131072

namespace cg = cooperative_groups;

using short8 = __attribute__((ext_vector_type(8))) short;
using f32x4  = __attribute__((ext_vector_type(4))) float;

__device__ __forceinline__ float rcpf(float x){ return __builtin_amdgcn_rcpf(x); }
__device__ __forceinline__ float sigm(float x){ return rcpf(1.0f+__expf(-x)); }
__device__ __forceinline__ float ftanh(float x){ float e=__expf(2.0f*x); return (e-1.0f)*rcpf(e+1.0f); }
__device__ __forceinline__ float swishf(float x){ return x*sigm(x); }
__device__ __forceinline__ float leaky(float x){ return x>=0.0f? x : 0.2f*x; }
__device__ __forceinline__ float dot4(float4 a, float4 b){ return a.x*b.x+a.y*b.y+a.z*b.z+a.w*b.w; }
__device__ __forceinline__ short f2bf(float x){
  unsigned u=__float_as_uint(x);
  unsigned r=(u + 0x7fffu + ((u>>16)&1u))>>16;
  return (short)r;
}
__device__ __forceinline__ int cvtpk(float a, float b){
  int r; asm("v_cvt_pk_bf16_f32 %0, %1, %2" : "=v"(r) : "v"(a), "v"(b)); return r;
}

__device__ __forceinline__ float wave_rsum(float v){
  #pragma unroll
  for(int m=32;m;m>>=1) v+=__shfl_xor(v,m);
  return v;
}

// ---------------- CSR build ----------------
__global__ __launch_bounds__(256) void hist_kernel(const int* __restrict__ dst, int* __restrict__ cnt){
  int e=blockIdx.x*256+threadIdx.x;
  if(e<N_EDGES) atomicAdd(&cnt[dst[e]],1);
}

__global__ __launch_bounds__(1024) void scan_kernel(const int* __restrict__ cnt, int* __restrict__ rowptr, int* __restrict__ cursor){
  __shared__ int sums[1024];
  int t=threadIdx.x; int base=t*8;
  int local[8]; int s=0;
  #pragma unroll
  for(int i=0;i<8;++i){ local[i]=s; s+=cnt[base+i]; }
  sums[t]=s; __syncthreads();
  for(int off=1;off<1024;off<<=1){
    int v=(t>=off)?sums[t-off]:0;
    __syncthreads();
    sums[t]+=v;
    __syncthreads();
  }
  int offset=(t>0)?sums[t-1]:0;
  #pragma unroll
  for(int i=0;i<8;++i){ int v=offset+local[i]; rowptr[base+i]=v; cursor[base+i]=v; }
  if(t==1023) rowptr[N_NODES]=sums[1023];
}

__global__ __launch_bounds__(256) void scatter_kernel(const int* __restrict__ src, const int* __restrict__ dst,
                                                      int* __restrict__ cursor, int* __restrict__ csr_src){
  int e=blockIdx.x*256+threadIdx.x;
  if(e<N_EDGES){
    int slot=atomicAdd(&cursor[dst[e]],1);
    csr_src[slot]=src[e];
  }
}

// ---------------- fused fp32 -> bf16 weight prep + edge-weight collapse ----------------
__global__ __launch_bounds__(256) void prep_bf16_kernel(
    const float* __restrict__ lem_hid_w, const float* __restrict__ lem_z_w,
    const float* __restrict__ mlp1_w, const float* __restrict__ mlp2_w,
    const float* __restrict__ gate_lin_w, const float* __restrict__ gnn_lin_w,
    const float* __restrict__ gate_ew, const float* __restrict__ gnn_ew,
    const float* __restrict__ gate_ae, const float* __restrict__ gnn_ae,
    short* __restrict__ whb, short* __restrict__ wzb, short* __restrict__ w1b,
    short* __restrict__ w2b, short* __restrict__ wlin16, float* __restrict__ we)
{
  int i=blockIdx.x*256+threadIdx.x;
  if(i<49152){ whb[i]=f2bf(lem_hid_w[i]); return; }
  if(i<65536){ int k=i-49152; wzb[k]=f2bf(lem_z_w[k]); return; }
  if(i<81920){ int k=i-65536; w1b[k]=f2bf(mlp1_w[k]); return; }
  if(i<98304){ int k=i-81920; w2b[k]=f2bf(mlp2_w[k]); return; }
  if(i<294912){
    int k=i-98304;                 // [6][2][16384]
    int l=k>>15, which=(k>>14)&1, r=k&16383;
    const float* s = which? gnn_lin_w + l*16384 + r : gate_lin_w + l*16384 + r;
    wlin16[k]=f2bf(*s);
    return;
  }
  int idx=i-294912;
  if(idx>=12*51) return;
  int g=idx/51, k=idx%51, l=g>>1;
  const float* ew = (g&1)? gnn_ew + l*128*51 : gate_ew + l*128*51;
  const float* ae = (g&1)? gnn_ae + l*128    : gate_ae + l*128;
  float s=0.f;
  for(int f=0;f<128;++f) s+=ew[f*51+k]*ae[f];
  we[idx]=s;
}

__global__ __launch_bounds__(128) void gsc_kernel(const float* __restrict__ u, const float* __restrict__ pos,
                                                  const float* __restrict__ we, float* __restrict__ gsc){
  int n=blockIdx.x*128+threadIdx.x;
  float uv[50];
  #pragma unroll
  for(int k=0;k<50;++k) uv[k]=u[n*50+k];
  float px=pos[n*2+1]*(1.0f/16.0f);
  for(int g=0;g<12;++g){
    const float* w=we+g*51;
    float s=w[50]*px;
    #pragma unroll
    for(int k=0;k<50;++k) s+=w[k]*uv[k];
    gsc[g*N_NODES+n]=s;
  }
}

// ---------------- shared device pieces ----------------
__device__ __forceinline__ void transform_phase(
    int tid, int n0,
    const short* __restrict__ h16, short* __restrict__ xts,
    float* __restrict__ ssred, float* __restrict__ sdred,
    const short* __restrict__ wl,
    const float* __restrict__ a_sg, const float* __restrict__ a_dg,
    const float* __restrict__ a_sm, const float* __restrict__ a_dm,
    const float* __restrict__ gsc_g, const float* __restrict__ gsc_m,
    short* __restrict__ xt_out, float* __restrict__ ss_out, float* __restrict__ sd_out)
{
  const int lane=tid&63, w=tid>>6;
  const int cg_=w&1, ch=w>>1;
  const int r16=lane&15, kq=lane>>4;
  __syncthreads();
  short8 afr[4];
  #pragma unroll
  for(int kk=0;kk<4;++kk)
    afr[kk]=*(const short8*)&h16[r16*128 + ((kk*32+kq*8) ^ ((r16&7)<<3))];
  const short* wb = wl + cg_*16384;
  const float* as_ = cg_? a_sm : a_sg;
  const float* ad_ = cg_? a_dm : a_dg;
  float ssp[4]={0,0,0,0}, sdp[4]={0,0,0,0};
  #pragma unroll
  for(int ci=0;ci<2;++ci){
    int c0=(ch*2+ci)*16;
    f32x4 acc={0.f,0.f,0.f,0.f};
    #pragma unroll
    for(int kk=0;kk<4;++kk){
      short8 b=*(const short8*)(wb + (c0+r16)*128 + kk*32 + kq*8);
      acc=__builtin_amdgcn_mfma_f32_16x16x32_bf16(afr[kk],b,acc,0,0,0);
    }
    float av=as_[c0+r16], dv=ad_[c0+r16];
    #pragma unroll
    for(int r=0;r<4;++r){
      ssp[r]+=acc[r]*av; sdp[r]+=acc[r]*dv;
      xts[(kq*4+r)*256 + cg_*128 + c0 + r16]=f2bf(acc[r]);
    }
  }
  #pragma unroll
  for(int m=1;m<16;m<<=1){
    #pragma unroll
    for(int r=0;r<4;++r){ ssp[r]+=__shfl_xor(ssp[r],m); sdp[r]+=__shfl_xor(sdp[r],m); }
  }
  if(r16==0){
    #pragma unroll
    for(int r=0;r<4;++r){ ssred[w*16+kq*4+r]=ssp[r]; sdred[w*16+kq*4+r]=sdp[r]; }
  }
  __syncthreads();
  if(tid<32){
    int node=tid&15, cg2=tid>>4;
    float sv=0.f, dv=0.f;
    #pragma unroll
    for(int c2=0;c2<4;++c2){ sv+=ssred[(c2*2+cg2)*16+node]; dv+=sdred[(c2*2+cg2)*16+node]; }
    float gv=(cg2? gsc_m:gsc_g)[n0+node];
    ss_out[2*(n0+node)+cg2]=sv+gv;
    sd_out[2*(n0+node)+cg2]=dv-gv;
  }
  {
    const short8* sp=(const short8*)xts;
    short8* dp=(short8*)(xt_out + (size_t)n0*256);
    dp[tid]=sp[tid];
  }
}

// Dual-GAT softmax aggregate for one node by one wave (single pass; clamp 60).
__device__ __forceinline__ float4 aggregate_node(
    int n, int lane, float4* __restrict__ stgw,
    const int* __restrict__ rowptr, const int* __restrict__ csr_src,
    const short* __restrict__ xt_in, const float* __restrict__ ss_in, const float* __restrict__ sd_in,
    const float* __restrict__ bias_g, const float* __restrict__ bias_m,
    const float* __restrict__ hrow)
{
  const int s0=rowptr[n], deg=rowptr[n+1]-s0;
  const float2 sdv=*(const float2*)(sd_in+2*n);
  const float bg=sdv.x, bm=sdv.y;
  float dg=0.f,dm=0.f, acc0=0.f,acc1=0.f,acc2=0.f,acc3=0.f;
  for(int c=0;c<deg;c+=64){
    int i=c+lane, s=0; float eg=0.f, em=0.f;
    if(i<deg){
      s=csr_src[s0+i];
      float2 ssv=*(const float2*)(ss_in+2*s);
      eg=__expf(fminf(leaky(ssv.x+bg),60.f));
      em=__expf(fminf(leaky(ssv.y+bm),60.f));
      dg+=eg; dm+=em;
    }
    float4 st; st.x=__int_as_float(s); st.y=eg; st.z=em; st.w=0.f;
    stgw[lane]=st;
    __threadfence_block();
    int cnt=min(64,deg-c);
    for(int cb=0;cb<cnt;cb+=8){
      int sj[8]; float wj[8];
      #pragma unroll
      for(int j=0;j<8;++j){
        int idx=cb+j;
        float4 ev=stgw[idx<cnt? idx : cb];
        sj[j]=__float_as_int(ev.x);
        wj[j]=(idx<cnt)? (lane<32? ev.y : ev.z) : 0.f;
      }
      uint2 rows[8];
      #pragma unroll
      for(int j=0;j<8;++j)
        rows[j]=*(const uint2*)(xt_in + (size_t)sj[j]*256 + 4*lane);
      #pragma unroll
      for(int j=0;j<8;++j){
        float wv=wj[j];
        unsigned p0=rows[j].x, p1=rows[j].y;
        acc0+=wv*__uint_as_float(p0<<16);
        acc1+=wv*__uint_as_float(p0&0xffff0000u);
        acc2+=wv*__uint_as_float(p1<<16);
        acc3+=wv*__uint_as_float(p1&0xffff0000u);
      }
    }
  }
  dg=wave_rsum(dg); dm=wave_rsum(dm);
  float rr = lane<32? rcpf(dg+1e-16f) : rcpf(dm+1e-16f);
  const float* bp = lane<32? bias_g+4*lane : bias_m+4*(lane-32);
  float4 bv=*(const float4*)bp;
  float o0=acc0*rr+bv.x, o1=acc1*rr+bv.y, o2=acc2*rr+bv.z, o3=acc3*rr+bv.w;
  float s0_=sigm(o0), s1_=sigm(o1), s2_=sigm(o2), s3_=sigm(o3);
  float v0=lane<32? s0_:o0*s0_;
  float v1=lane<32? s1_:o1*s1_;
  float v2=lane<32? s2_:o2*s2_;
  float v3=lane<32? s3_:o3*s3_;
  float m0=__shfl_xor(v0,32), m1=__shfl_xor(v1,32), m2=__shfl_xor(v2,32), m3=__shfl_xor(v3,32);
  float4 r;
  if(lane<32){
    float4 hv=*(const float4*)(hrow + 4*lane);
    r.x=(1.0f-v0)*hv.x+v0*m0;
    r.y=(1.0f-v1)*hv.y+v1*m1;
    r.z=(1.0f-v2)*hv.z+v2*m2;
    r.w=(1.0f-v3)*hv.w+v3*m3;
  } else { r.x=r.y=r.z=r.w=0.f; }
  return r;
}

// ---------------- LEM scan (MFMA, 32 nodes/block) + MLP + GAT transform layer 0 ----------------
__global__ __launch_bounds__(512,2) void lem_t0_kernel(
    const float* __restrict__ u, const float* __restrict__ pos,
    const float* __restrict__ Wi, const float* __restrict__ bi,
    const short* __restrict__ whb, const float* __restrict__ bh,
    const short* __restrict__ wzb, const float* __restrict__ bz,
    const short* __restrict__ w1b, const float* __restrict__ b1,
    const short* __restrict__ w2b, const float* __restrict__ b2,
    float* __restrict__ hout,
    const short* __restrict__ wl,
    const float* __restrict__ a_sg, const float* __restrict__ a_dg,
    const float* __restrict__ a_sm, const float* __restrict__ a_dm,
    const float* __restrict__ gsc_g, const float* __restrict__ gsc_m,
    short* __restrict__ xt_out, float* __restrict__ ss_out, float* __restrict__ sd_out)
{
  __shared__ short y16[2][16*128];
  __shared__ short z16[2][16*128];
  __shared__ float u_s[32*50];
  __shared__ short h16[16*128];
  __shared__ short xts[16*256];
  __shared__ float ssred[128], sdred[128];

  const int tid=threadIdx.x, lane=tid&63, w=tid>>6;
  const int node=lane&15, q=lane>>4;
  const int n7=node&7;
  const int n0=blockIdx.x*32;

  for(int i=tid;i<32*50;i+=512) u_s[i]=u[n0*50+i];
  for(int i=tid;i<2*16*64;i+=512) ((int*)y16)[i]=0;

  const float px0=pos[(n0+node)*2+1]*(1.0f/16.0f),    pt0=pos[(n0+node)*2+0]*0.25f;
  const float px1=pos[(n0+16+node)*2+1]*(1.0f/16.0f), pt1=pos[(n0+16+node)*2+0]*0.25f;

  float bb[4][4], wix[4][4], wiw[4][4], wiy[4][4], wiz[4][4];
  #pragma unroll
  for(int gg=0; gg<4; ++gg){
    #pragma unroll
    for(int r=0;r<4;++r){
      int fr = w*16+q*4+r;
      int row = gg*128+fr;
      float4 wi = *(const float4*)(Wi+4*row);
      bb[gg][r] = bi[row] + ((gg<3)? bh[row] : bz[fr]);
      wix[gg][r]=wi.x; wiw[gg][r]=wi.w; wiy[gg][r]=wi.y; wiz[gg][r]=wi.z;
    }
  }

  short8 whf[3][4];
  #pragma unroll
  for(int gg=0;gg<3;++gg)
    #pragma unroll
    for(int kk=0;kk<4;++kk)
      whf[gg][kk]=*(const short8*)(whb + (gg*128 + w*16 + node)*128 + kk*32 + q*8);
  short8 wzf[4];
  #pragma unroll
  for(int kk=0;kk<4;++kk)
    wzf[kk]=*(const short8*)(wzb + (w*16 + node)*128 + kk*32 + q*8);

  float yr0[4]={0.f,0.f,0.f,0.f}, zr0[4]={0.f,0.f,0.f,0.f};
  float yr1[4]={0.f,0.f,0.f,0.f}, zr1[4]={0.f,0.f,0.f,0.f};
  float msb0[4], i4s0[4], msb1[4], i4s1[4];
  const int wrslot = (w*16+q*4) ^ (n7<<3);
  const int rdbase = n7<<3;
  __syncthreads();

  for(int t=0;t<25;++t){
    const float tf=(float)(t+1);
    {
      f32x4 h1a={0.f,0.f,0.f,0.f}, h2a=h1a, h3a=h1a;
      #pragma unroll
      for(int kk=0;kk<4;++kk){
        short8 yb=*(const short8*)&y16[0][node*128 + ((kk*32 + q*8) ^ rdbase)];
        h1a=__builtin_amdgcn_mfma_f32_16x16x32_bf16(whf[0][kk],yb,h1a,0,0,0);
        h2a=__builtin_amdgcn_mfma_f32_16x16x32_bf16(whf[1][kk],yb,h2a,0,0,0);
        h3a=__builtin_amdgcn_mfma_f32_16x16x32_bf16(whf[2][kk],yb,h3a,0,0,0);
      }
      const float u0=u_s[node*50+t], u1=u_s[node*50+25+t];
      const float ts=pt0+0.04f*tf;
      #pragma unroll
      for(int r=0;r<4;++r){
        float i1=bb[0][r]+wix[0][r]*px0+wiw[0][r]*ts+wiy[0][r]*u0+wiz[0][r]*u1;
        float i2=bb[1][r]+wix[1][r]*px0+wiw[1][r]*ts+wiy[1][r]*u0+wiz[1][r]*u1;
        float i3=bb[2][r]+wix[2][r]*px0+wiw[2][r]*ts+wiy[2][r]*u0+wiz[2][r]*u1;
        i4s0[r] =bb[3][r]+wix[3][r]*px0+wiw[3][r]*ts+wiy[3][r]*u0+wiz[3][r]*u1;
        msb0[r]=sigm(i1+h1a[r]);
        float ms=sigm(i2+h2a[r]);
        zr0[r]=(1.0f-ms)*zr0[r]+ms*ftanh(i3+h3a[r]);
      }
      int2 zz; zz.x=cvtpk(zr0[0],zr0[1]); zz.y=cvtpk(zr0[2],zr0[3]);
      *(int2*)&z16[0][node*128 + wrslot]=zz;
    }
    {
      f32x4 h1a={0.f,0.f,0.f,0.f}, h2a=h1a, h3a=h1a;
      #pragma unroll
      for(int kk=0;kk<4;++kk){
        short8 yb=*(const short8*)&y16[1][node*128 + ((kk*32 + q*8) ^ rdbase)];
        h1a=__builtin_amdgcn_mfma_f32_16x16x32_bf16(whf[0][kk],yb,h1a,0,0,0);
        h2a=__builtin_amdgcn_mfma_f32_16x16x32_bf16(whf[1][kk],yb,h2a,0,0,0);
        h3a=__builtin_amdgcn_mfma_f32_16x16x32_bf16(whf[2][kk],yb,h3a,0,0,0);
      }
      const float u0=u_s[(16+node)*50+t], u1=u_s[(16+node)*50+25+t];
      const float ts=pt1+0.04f*tf;
      #pragma unroll
      for(int r=0;r<4;++r){
        float i1=bb[0][r]+wix[0][r]*px1+wiw[0][r]*ts+wiy[0][r]*u0+wiz[0][r]*u1;
        float i2=bb[1][r]+wix[1][r]*px1+wiw[1][r]*ts+wiy[1][r]*u0+wiz[1][r]*u1;
        float i3=bb[2][r]+wix[2][r]*px1+wiw[2][r]*ts+wiy[2][r]*u0+wiz[2][r]*u1;
        i4s1[r] =bb[3][r]+wix[3][r]*px1+wiw[3][r]*ts+wiy[3][r]*u0+wiz[3][r]*u1;
        msb1[r]=sigm(i1+h1a[r]);
        float ms=sigm(i2+h2a[r]);
        zr1[r]=(1.0f-ms)*zr1[r]+ms*ftanh(i3+h3a[r]);
      }
      int2 zz; zz.x=cvtpk(zr1[0],zr1[1]); zz.y=cvtpk(zr1[2],zr1[3]);
      *(int2*)&z16[1][node*128 + wrslot]=zz;
    }
    __syncthreads();
    {
      f32x4 zw={0.f,0.f,0.f,0.f};
      #pragma unroll
      for(int kk=0;kk<4;++kk){
        short8 zb=*(const short8*)&z16[0][node*128 + ((kk*32 + q*8) ^ rdbase)];
        zw=__builtin_amdgcn_mfma_f32_16x16x32_bf16(wzf[kk],zb,zw,0,0,0);
      }
      #pragma unroll
      for(int r=0;r<4;++r)
        yr0[r]=(1.0f-msb0[r])*yr0[r]+msb0[r]*ftanh(zw[r]+i4s0[r]);
      int2 yy; yy.x=cvtpk(yr0[0],yr0[1]); yy.y=cvtpk(yr0[2],yr0[3]);
      *(int2*)&y16[0][node*128 + wrslot]=yy;
    }
    {
      f32x4 zw={0.f,0.f,0.f,0.f};
      #pragma unroll
      for(int kk=0;kk<4;++kk){
        short8 zb=*(const short8*)&z16[1][node*128 + ((kk*32 + q*8) ^ rdbase)];
        zw=__builtin_amdgcn_mfma_f32_16x16x32_bf16(wzf[kk],zb,zw,0,0,0);
      }
      #pragma unroll
      for(int r=0;r<4;++r)
        yr1[r]=(1.0f-msb1[r])*yr1[r]+msb1[r]*ftanh(zw[r]+i4s1[r]);
      int2 yy; yy.x=cvtpk(yr1[0],yr1[1]); yy.y=cvtpk(yr1[2],yr1[3]);
      *(int2*)&y16[1][node*128 + wrslot]=yy;
    }
    __syncthreads();
  }

  #pragma unroll
  for(int nt=0;nt<2;++nt){
    {
      short8 w1f[4];
      #pragma unroll
      for(int kk=0;kk<4;++kk)
        w1f[kk]=*(const short8*)(w1b + (w*16 + node)*128 + kk*32 + q*8);
      float4 b1v=*(const float4*)(b1 + w*16 + q*4);
      f32x4 a={0.f,0.f,0.f,0.f};
      #pragma unroll
      for(int kk=0;kk<4;++kk){
        short8 yb=*(const short8*)&y16[nt][node*128 + ((kk*32 + q*8) ^ rdbase)];
        a=__builtin_amdgcn_mfma_f32_16x16x32_bf16(w1f[kk],yb,a,0,0,0);
      }
      float t0=swishf(a[0]+b1v.x), t1=swishf(a[1]+b1v.y);
      float t2=swishf(a[2]+b1v.z), t3=swishf(a[3]+b1v.w);
      int2 zz; zz.x=cvtpk(t0,t1); zz.y=cvtpk(t2,t3);
      *(int2*)&z16[nt][node*128 + wrslot]=zz;
    }
    __syncthreads();
    {
      short8 w2f[4];
      #pragma unroll
      for(int kk=0;kk<4;++kk)
        w2f[kk]=*(const short8*)(w2b + (w*16 + node)*128 + kk*32 + q*8);
      float4 b2v=*(const float4*)(b2 + w*16 + q*4);
      f32x4 a={0.f,0.f,0.f,0.f};
      #pragma unroll
      for(int kk=0;kk<4;++kk){
        short8 zb=*(const short8*)&z16[nt][node*128 + ((kk*32 + q*8) ^ rdbase)];
        a=__builtin_amdgcn_mfma_f32_16x16x32_bf16(w2f[kk],zb,a,0,0,0);
      }
      float h0=swishf(a[0]+b2v.x), h1=swishf(a[1]+b2v.y);
      float h2=swishf(a[2]+b2v.z), h3=swishf(a[3]+b2v.w);
      float4 hv; hv.x=h0; hv.y=h1; hv.z=h2; hv.w=h3;
      *(float4*)(hout + (size_t)(n0+nt*16+node)*128 + w*16+q*4)=hv;
      int2 hb; hb.x=cvtpk(h0,h1); hb.y=cvtpk(h2,h3);
      *(int2*)&h16[node*128 + wrslot]=hb;
    }
    transform_phase(tid,n0+nt*16,h16,xts,ssred,sdred,wl,a_sg,a_dg,a_sm,a_dm,gsc_g,gsc_m,xt_out,ss_out,sd_out);
  }
}

// ---------------- persistent GAT chain (6 layers) + decoder, cooperative ----------------
// 256 blocks x 512 threads; block owns 32 nodes (2 tiles of 16); h in LDS across layers.
// LDS: 16KB hfp + union(21KB gat, 37.8KB dec) = 52.9KB <= 64KB per-workgroup limit.
__global__ __launch_bounds__(512,2) void gnn_persist_kernel(
    const int* __restrict__ rowptr, const int* __restrict__ csr_src,
    const float* __restrict__ hin,
    short* __restrict__ xtA, float* __restrict__ ssA, float* __restrict__ sdA,
    short* __restrict__ xtB, float* __restrict__ ssB, float* __restrict__ sdB,
    const short* __restrict__ wlin16,
    const float* __restrict__ gate_att_src, const float* __restrict__ gate_att_dst,
    const float* __restrict__ gnn_att_src, const float* __restrict__ gnn_att_dst,
    const float* __restrict__ gsc,
    const float* __restrict__ gate_bias, const float* __restrict__ gnn_bias,
    const float* __restrict__ u,
    const float* __restrict__ Wd, const float* __restrict__ bd,
    const float* __restrict__ w1, const float* __restrict__ b1,
    const float* __restrict__ w2, const float* __restrict__ b2,
    float* __restrict__ out)
{
  __shared__ float hfp[32*128];
  __shared__ union SM {
    struct {
      short h16[16*128];
      short xts[16*256];
      float ssred[128], sdred[128];
      float4 stg[8][64];
    } g;
    struct {
      float h2[16][2][128];
      float c1[16][8][38];
      float w1s[256], w2s[224], b1s[8], b2s[2];
    } d;
  } sm;

  cg::grid_group grid = cg::this_grid();
  const int tid=threadIdx.x, lane=tid&63, w=tid>>6;
  const int n0=blockIdx.x*32;

  for(int i=tid;i<32*128;i+=512) hfp[i]=hin[(size_t)n0*128+i];
  __syncthreads();

  for(int l=0;l<6;++l){
    const short* xt_in = (l&1)? xtB : xtA;
    const float* ss_in = (l&1)? ssB : ssA;
    const float* sd_in = (l&1)? sdB : sdA;
    const float* bias_g = gate_bias + l*128;
    const float* bias_m = gnn_bias + l*128;
    #pragma unroll
    for(int nt=0;nt<2;++nt){
      // aggregate tile nt (16 nodes; wave w -> local rows 2w, 2w+1)
      #pragma unroll
      for(int which=0;which<2;++which){
        int rl=w*2+which;               // row within tile
        int row=nt*16+rl;               // row within block
        int n=n0+row;
        float4 hv=aggregate_node(n,lane,sm.g.stg[w],rowptr,csr_src,xt_in,ss_in,sd_in,bias_g,bias_m,&hfp[row*128]);
        if(lane<32){
          *(float4*)&hfp[row*128+4*lane]=hv;
          int2 hb; hb.x=cvtpk(hv.x,hv.y); hb.y=cvtpk(hv.z,hv.w);
          *(int2*)&sm.g.h16[rl*128 + ((4*lane) ^ ((rl&7)<<3))]=hb;
        }
      }
      if(l<5){
        int lp=l+1;
        transform_phase(tid,n0+nt*16,sm.g.h16,sm.g.xts,sm.g.ssred,sm.g.sdred,
          wlin16+(size_t)lp*32768,
          gate_att_src+lp*128, gate_att_dst+lp*128,
          gnn_att_src+lp*128, gnn_att_dst+lp*128,
          gsc+(size_t)(2*lp)*N_NODES, gsc+(size_t)(2*lp+1)*N_NODES,
          (l&1)? xtA:xtB, (l&1)? ssA:ssB, (l&1)? sdA:sdB);
      }
    }
    if(l<5){
      __threadfence();
      grid.sync();
      __threadfence();
    }
  }

  // ---- decoder on hfp (2 tiles of 16 nodes) ----
  __syncthreads();
  if(tid<256) sm.d.w1s[tid]=w1[tid];
  else if(tid<480) sm.d.w2s[tid-256]=w2[tid-256];
  else if(tid<488) sm.d.b1s[tid-480]=b1[tid-480];
  else if(tid<490) sm.d.b2s[tid-488]=b2[tid-488];
  __syncthreads();
  for(int nt=0;nt<2;++nt){
    const float* hbase=&hfp[nt*16*128];
    {
      int o=tid&255, grp=tid>>8;
      const float4* wp=(const float4*)(Wd + o*128);
      float acc[8];
      #pragma unroll
      for(int n=0;n<8;++n) acc[n]=0.f;
      for(int k=0;k<32;++k){
        float4 wv=wp[k];
        #pragma unroll
        for(int n=0;n<8;++n){ float4 hval=*(const float4*)&hbase[(grp*8+n)*128+k*4]; acc[n]+=dot4(wv,hval); }
      }
      float bdv=bd[o];
      int chn=o>>7, p=o&127;
      #pragma unroll
      for(int n=0;n<8;++n) sm.d.h2[grp*8+n][chn][p]=swishf(acc[n]+bdv);
    }
    __syncthreads();
    for(int idx=tid; idx<16*8*38; idx+=512){
      int n=idx/(8*38); int r=idx%(8*38); int oc=r/38, p=r%38;
      float acc=sm.d.b1s[oc];
      const float* ww=&sm.d.w1s[oc*32];
      #pragma unroll
      for(int ic=0;ic<2;++ic)
        #pragma unroll
        for(int k=0;k<16;++k) acc+=ww[ic*16+k]*sm.d.h2[n][ic][3*p+k];
      sm.d.c1[n][oc][p]=swishf(acc);
    }
    __syncthreads();
    for(int idx=tid; idx<16*2*25; idx+=512){
      int n=idx/50; int r=idx%50; int oc=r/25, p=r%25;
      float acc=sm.d.b2s[oc];
      const float* ww=&sm.d.w2s[oc*112];
      #pragma unroll
      for(int ic=0;ic<8;++ic)
        #pragma unroll
        for(int k=0;k<14;++k) acc+=ww[ic*14+k]*sm.d.c1[n][ic][p+k];
      int col=oc*25+p;
      int gn=n0+nt*16+n;
      out[gn*50+col]=u[gn*50+col]+0.04f*(float)(p+1)*acc;
    }
    __syncthreads();
  }
}

// ---------------- fallback: aggregate(l)+transform(l+1) (round-7 proven path) ----------------
__global__ __launch_bounds__(512,2) void gat_fused_kernel(
    const int* __restrict__ rowptr, const int* __restrict__ csr_src,
    const short* __restrict__ xt_in, const float* __restrict__ ss_in, const float* __restrict__ sd_in,
    const float* __restrict__ bias_g, const float* __restrict__ bias_m,
    float* __restrict__ h,
    const short* __restrict__ wl,
    const float* __restrict__ a_sg, const float* __restrict__ a_dg,
    const float* __restrict__ a_sm, const float* __restrict__ a_dm,
    const float* __restrict__ gsc_g, const float* __restrict__ gsc_m,
    short* __restrict__ xt_out, float* __restrict__ ss_out, float* __restrict__ sd_out)
{
  __shared__ short h16[16*128];
  __shared__ short xts[16*256];
  __shared__ float ssred[128], sdred[128];
  __shared__ float4 stg[8][64];
  const int tid=threadIdx.x, lane=tid&63, w=tid>>6;
  const int n0=blockIdx.x*16;
  #pragma unroll
  for(int which=0;which<2;++which){
    int row=w*2+which, n=n0+row;
    float4 hv=aggregate_node(n,lane,stg[w],rowptr,csr_src,xt_in,ss_in,sd_in,bias_g,bias_m,h+(size_t)n*128);
    if(lane<32){
      *(float4*)(h+(size_t)n*128+4*lane)=hv;
      int2 hb; hb.x=cvtpk(hv.x,hv.y); hb.y=cvtpk(hv.z,hv.w);
      *(int2*)&h16[row*128 + ((4*lane) ^ ((row&7)<<3))]=hb;
    }
  }
  transform_phase(tid,n0,h16,xts,ssred,sdred,wl,a_sg,a_dg,a_sm,a_dm,gsc_g,gsc_m,xt_out,ss_out,sd_out);
}

__global__ __launch_bounds__(512,2) void gat_last_decoder_kernel(
    const int* __restrict__ rowptr, const int* __restrict__ csr_src,
    const short* __restrict__ xt_in, const float* __restrict__ ss_in, const float* __restrict__ sd_in,
    const float* __restrict__ bias_g, const float* __restrict__ bias_m,
    const float* __restrict__ h, const float* __restrict__ u,
    const float* __restrict__ Wd, const float* __restrict__ bd,
    const float* __restrict__ w1, const float* __restrict__ b1,
    const float* __restrict__ w2, const float* __restrict__ b2,
    float* __restrict__ out)
{
  __shared__ float hdec[16*128];
  __shared__ float h2[16][2][128];
  __shared__ float c1[16][8][38];
  __shared__ float w1s[256], w2s[224], b1s[8], b2s[2];
  __shared__ float4 stg[8][64];
  const int tid=threadIdx.x, lane=tid&63, w=tid>>6;
  const int n0=blockIdx.x*16;
  if(tid<256) w1s[tid]=w1[tid];
  else if(tid<480) w2s[tid-256]=w2[tid-256];
  else if(tid<488) b1s[tid-480]=b1[tid-480];
  else if(tid<490) b2s[tid-488]=b2[tid-488];
  #pragma unroll
  for(int which=0;which<2;++which){
    int row=w*2+which, n=n0+row;
    float4 hv=aggregate_node(n,lane,stg[w],rowptr,csr_src,xt_in,ss_in,sd_in,bias_g,bias_m,h+(size_t)n*128);
    if(lane<32) *(float4*)&hdec[row*128+4*lane]=hv;
  }
  __syncthreads();
  {
    int o=tid&255, grp=tid>>8;
    const float4* wp=(const float4*)(Wd + o*128);
    float acc[8];
    #pragma unroll
    for(int n=0;n<8;++n) acc[n]=0.f;
    for(int k=0;k<32;++k){
      float4 wv=wp[k];
      #pragma unroll
      for(int n=0;n<8;++n){ float4 hval=*(const float4*)&hdec[(grp*8+n)*128+k*4]; acc[n]+=dot4(wv,hval); }
    }
    float bdv=bd[o];
    int chn=o>>7, p=o&127;
    #pragma unroll
    for(int n=0;n<8;++n) h2[grp*8+n][chn][p]=swishf(acc[n]+bdv);
  }
  __syncthreads();
  for(int idx=tid; idx<16*8*38; idx+=512){
    int n=idx/(8*38); int r=idx%(8*38); int oc=r/38, p=r%38;
    float acc=b1s[oc];
    const float* ww=&w1s[oc*32];
    #pragma unroll
    for(int ic=0;ic<2;++ic)
      #pragma unroll
      for(int k=0;k<16;++k) acc+=ww[ic*16+k]*h2[n][ic][3*p+k];
    c1[n][oc][p]=swishf(acc);
  }
  __syncthreads();
  for(int idx=tid; idx<16*2*25; idx+=512){
    int n=idx/50; int r=idx%50; int oc=r/25, p=r%25;
    float acc=b2s[oc];
    const float* ww=&w2s[oc*112];
    #pragma unroll
    for(int ic=0;ic<8;++ic)
      #pragma unroll
      for(int k=0;k<14;++k) acc+=ww[ic*14+k]*c1[n][ic][p+k];
    int col=oc*25+p;
    out[(n0+n)*50+col]=u[(n0+n)*50+col]+0.04f*(float)(p+1)*acc;
  }
}

extern "C" void kernel_launch(void* const* d_in, const int* in_sizes, int n_in,
                              void* d_out, int out_size, void* d_ws, size_t ws_size,
                              hipStream_t stream)
{
  const float* u          =(const float*)d_in[0];
  const float* pos        =(const float*)d_in[1];
  const int*   ei         =(const int*)d_in[2];
  const float* lem_inp_w  =(const float*)d_in[3];
  const float* lem_inp_b  =(const float*)d_in[4];
  const float* lem_hid_w  =(const float*)d_in[5];
  const float* lem_hid_b  =(const float*)d_in[6];
  const float* lem_z_w    =(const float*)d_in[7];
  const float* lem_z_b    =(const float*)d_in[8];
  const float* mlp1_w     =(const float*)d_in[9];
  const float* mlp1_b     =(const float*)d_in[10];
  const float* mlp2_w     =(const float*)d_in[11];
  const float* mlp2_b     =(const float*)d_in[12];
  const float* gnn_lin_w  =(const float*)d_in[13];
  const float* gnn_edge_w =(const float*)d_in[14];
  const float* gnn_att_src=(const float*)d_in[15];
  const float* gnn_att_dst=(const float*)d_in[16];
  const float* gnn_att_edge=(const float*)d_in[17];
  const float* gnn_bias   =(const float*)d_in[18];
  const float* gate_lin_w =(const float*)d_in[19];
  const float* gate_edge_w=(const float*)d_in[20];
  const float* gate_att_src=(const float*)d_in[21];
  const float* gate_att_dst=(const float*)d_in[22];
  const float* gate_att_edge=(const float*)d_in[23];
  const float* gate_bias  =(const float*)d_in[24];
  const float* dbl_w      =(const float*)d_in[25];
  const float* dbl_b      =(const float*)d_in[26];
  const float* conv1_w    =(const float*)d_in[27];
  const float* conv1_b    =(const float*)d_in[28];
  const float* conv2_w    =(const float*)d_in[29];
  const float* conv2_b    =(const float*)d_in[30];
  float* out=(float*)d_out;

  char* ws=(char*)d_ws;
  size_t off=0;
  auto alloc=[&](size_t bytes)->char*{ char* p=ws+off; off+=(bytes+255)&~(size_t)255; return p; };
  float* h    =(float*)alloc((size_t)N_NODES*128*4);
  short* xtA  =(short*)alloc((size_t)N_NODES*256*2);
  short* xtB  =(short*)alloc((size_t)N_NODES*256*2);
  float* ssA  =(float*)alloc((size_t)N_NODES*2*4);
  float* ssB  =(float*)alloc((size_t)N_NODES*2*4);
  float* sdA  =(float*)alloc((size_t)N_NODES*2*4);
  float* sdB  =(float*)alloc((size_t)N_NODES*2*4);
  float* gsc  =(float*)alloc((size_t)12*N_NODES*4);
  float* wearr=(float*)alloc(12*51*4);
  int* cnt    =(int*)alloc(N_NODES*4);
  int* rowptr =(int*)alloc((N_NODES+8)*4);
  int* cursor =(int*)alloc(N_NODES*4);
  int* csrsrc =(int*)alloc((size_t)N_EDGES*4);
  short* whb  =(short*)alloc(384*128*2);
  short* wzb  =(short*)alloc(128*128*2);
  short* w1b  =(short*)alloc(128*128*2);
  short* w2b  =(short*)alloc(128*128*2);
  short* wlin16=(short*)alloc((size_t)6*2*128*128*2);

  const int* src=ei;
  const int* dst=ei+N_EDGES;

  hipMemsetAsync(cnt,0,N_NODES*4,stream);
  hist_kernel<<<N_EDGES/256,256,0,stream>>>(dst,cnt);
  scan_kernel<<<1,1024,0,stream>>>(cnt,rowptr,cursor);
  scatter_kernel<<<N_EDGES/256,256,0,stream>>>(src,dst,cursor,csrsrc);
  prep_bf16_kernel<<<(294912+612+255)/256,256,0,stream>>>(lem_hid_w,lem_z_w,mlp1_w,mlp2_w,
                                                      gate_lin_w,gnn_lin_w,
                                                      gate_edge_w,gnn_edge_w,gate_att_edge,gnn_att_edge,
                                                      whb,wzb,w1b,w2b,wlin16,wearr);
  gsc_kernel<<<N_NODES/128,128,0,stream>>>(u,pos,wearr,gsc);

  lem_t0_kernel<<<N_NODES/32,512,0,stream>>>(u,pos,lem_inp_w,lem_inp_b,whb,lem_hid_b,
      wzb,lem_z_b,w1b,mlp1_b,w2b,mlp2_b,h,
      wlin16,
      gate_att_src, gate_att_dst, gnn_att_src, gnn_att_dst,
      gsc, gsc+(size_t)N_NODES,
      xtA, ssA, sdA);

  // cooperative path if the persist kernel can co-reside (256 blocks @ >=1/CU)
  int occ=0;
  hipError_t qerr=hipOccupancyMaxActiveBlocksPerMultiprocessor(&occ,
      reinterpret_cast<const void*>(gnn_persist_kernel), 512, 0);
  bool coop = (qerr==hipSuccess) && (occ>=1);

  if(coop){
    void* kargs[]={
      (void*)&rowptr,(void*)&csrsrc,(void*)&h,
      (void*)&xtA,(void*)&ssA,(void*)&sdA,
      (void*)&xtB,(void*)&ssB,(void*)&sdB,
      (void*)&wlin16,
      (void*)&gate_att_src,(void*)&gate_att_dst,(void*)&gnn_att_src,(void*)&gnn_att_dst,
      (void*)&gsc,
      (void*)&gate_bias,(void*)&gnn_bias,
      (void*)&u,(void*)&dbl_w,(void*)&dbl_b,
      (void*)&conv1_w,(void*)&conv1_b,(void*)&conv2_w,(void*)&conv2_b,
      (void*)&out
    };
    hipError_t lerr=hipLaunchCooperativeKernel((void*)gnn_persist_kernel,
        dim3(N_NODES/32), dim3(512), kargs, 0, stream);
    if(lerr==hipSuccess) return;
  }

  // fallback: proven round-7 sequence
  for(int l=0;l<5;++l){
    short* xin = (l&1)? xtB:xtA;  float* sin_=(l&1)? ssA:ssA; // placeholder, fixed below
    (void)xin; (void)sin_;
  }
  {
    short* xtbuf[2]={xtA,xtB};
    float* ssbuf[2]={ssA,ssB};
    float* sdbuf[2]={sdA,sdB};
    for(int l=0;l<5;++l){
      int in=l&1, o2=(l+1)&1;
      gat_fused_kernel<<<N_NODES/16,512,0,stream>>>(rowptr,csrsrc,
        xtbuf[in],ssbuf[in],sdbuf[in],
        gate_bias+l*128, gnn_bias+l*128, h,
        wlin16+(size_t)(l+1)*2*16384,
        gate_att_src+(l+1)*128, gate_att_dst+(l+1)*128,
        gnn_att_src+(l+1)*128, gnn_att_dst+(l+1)*128,
        gsc+(size_t)(2*(l+1))*N_NODES, gsc+(size_t)(2*(l+1)+1)*N_NODES,
        xtbuf[o2], ssbuf[o2], sdbuf[o2]);
    }
    gat_last_decoder_kernel<<<N_NODES/16,512,0,stream>>>(rowptr,csrsrc,
        xtbuf[1],ssbuf[1],sdbuf[1],
        gate_bias+5*128, gnn_bias+5*128, h, u,
        dbl_w, dbl_b, conv1_w, conv1_b, conv2_w, conv2_b, out);
  }
}